// Round 1
// baseline (576.225 us; speedup 1.0000x reference)
//
#include <hip/hip_runtime.h>
#include <math.h>

#define NB   16
#define CCH  256
#define NN   1024    // 32*32
#define NHEAD 4
#define DKK  64
#define J3   768     // 4*64*3

// ---------------- Kernel 1: qkv[m, j] = sum_c x[b,c,n]*W[c,j] + bias[j] ----
// x: [B, C, N] (n contiguous), W: [256, 768], qkv: [B*N, 768]
__global__ __launch_bounds__(256) void qkv_gemm(
    const float* __restrict__ x, const float* __restrict__ W,
    const float* __restrict__ bias, float* __restrict__ qkv)
{
    __shared__ float As[16 * 128];   // [k][m]
    __shared__ float Bs[16 * 128];   // [k][j]
    const int j0 = blockIdx.x * 128;     // 768/128 = 6
    const int m0 = blockIdx.y * 128;     // 16384/128 = 128
    const int b  = m0 >> 10;
    const int n0 = m0 & 1023;            // tiles never straddle batches
    const int t  = threadIdx.x;
    const int g  = t >> 4;               // 0..15
    const int mm = t & 15;               // 0..15
    const float* xb = x + (size_t)b * CCH * NN + n0;

    float acc[2][4][2][4];               // [rowblk][i][colblk][j]
    #pragma unroll
    for (int rb = 0; rb < 2; ++rb)
        #pragma unroll
        for (int i = 0; i < 4; ++i)
            #pragma unroll
            for (int cb = 0; cb < 2; ++cb)
                #pragma unroll
                for (int j = 0; j < 4; ++j) acc[rb][i][cb][j] = 0.f;

    for (int k0 = 0; k0 < CCH; k0 += 16) {
        #pragma unroll
        for (int i = 0; i < 8; ++i) {
            int idx = t + 256 * i;
            int k = idx >> 7, p = idx & 127;
            As[k * 128 + p] = xb[(size_t)(k0 + k) * NN + p];
            Bs[k * 128 + p] = W[(size_t)(k0 + k) * J3 + j0 + p];
        }
        __syncthreads();
        #pragma unroll
        for (int k = 0; k < 16; ++k) {
            float4 a0 = *(const float4*)&As[k * 128 + 4 * g];
            float4 a1 = *(const float4*)&As[k * 128 + 64 + 4 * g];
            float4 b0 = *(const float4*)&Bs[k * 128 + 4 * mm];
            float4 b1 = *(const float4*)&Bs[k * 128 + 64 + 4 * mm];
            float ar[2][4] = {{a0.x, a0.y, a0.z, a0.w}, {a1.x, a1.y, a1.z, a1.w}};
            float br[2][4] = {{b0.x, b0.y, b0.z, b0.w}, {b1.x, b1.y, b1.z, b1.w}};
            #pragma unroll
            for (int rb = 0; rb < 2; ++rb)
                #pragma unroll
                for (int i = 0; i < 4; ++i)
                    #pragma unroll
                    for (int cb = 0; cb < 2; ++cb)
                        #pragma unroll
                        for (int j = 0; j < 4; ++j)
                            acc[rb][i][cb][j] += ar[rb][i] * br[cb][j];
        }
        __syncthreads();
    }

    float bb[2][4];
    #pragma unroll
    for (int cb = 0; cb < 2; ++cb) {
        float4 bv = *(const float4*)&bias[j0 + cb * 64 + 4 * mm];
        bb[cb][0] = bv.x; bb[cb][1] = bv.y; bb[cb][2] = bv.z; bb[cb][3] = bv.w;
    }
    #pragma unroll
    for (int rb = 0; rb < 2; ++rb)
        #pragma unroll
        for (int i = 0; i < 4; ++i) {
            int row = m0 + rb * 64 + 4 * g + i;
            #pragma unroll
            for (int cb = 0; cb < 2; ++cb) {
                float4 v;
                v.x = acc[rb][i][cb][0] + bb[cb][0];
                v.y = acc[rb][i][cb][1] + bb[cb][1];
                v.z = acc[rb][i][cb][2] + bb[cb][2];
                v.w = acc[rb][i][cb][3] + bb[cb][3];
                *(float4*)&qkv[(size_t)row * J3 + j0 + cb * 64 + 4 * mm] = v;
            }
        }
}

// ---------------- Kernel 2: flash attention per (b, h, q-tile of 64) -------
// qkv layout per row (768): head h at h*192 + {q:0..63, k:64..127, v:128..191}
// res: [B*N, 256] with col = h*64 + d
__global__ __launch_bounds__(256) void flash_attn(
    const float* __restrict__ qkv, float* __restrict__ res)
{
    __shared__ float Qs[64 * 68];
    __shared__ float Ks[64 * 68];   // reused as P after S-compute
    __shared__ float Vs[64 * 68];
    const int blk = blockIdx.x;
    const int qt = blk & 15;
    const int h  = (blk >> 4) & 3;
    const int b  = blk >> 6;
    const int t  = threadIdx.x;
    const int g  = t >> 4;          // 0..15 -> row group
    const int mm = t & 15;          // 0..15 -> col group
    const int tr = g * 4;           // 4 rows per thread
    const int tj = mm * 4;          // 4 cols per thread
    const float scale = 0.125f;     // 64^-0.5

    const float* qbase = qkv + ((size_t)b * NN) * J3 + h * 192;

    // Load Q tile (pre-scaled)
    #pragma unroll
    for (int i = 0; i < 4; ++i) {
        int idx = t + 256 * i;
        int row = idx >> 4, c4 = idx & 15;
        float4 v = *(const float4*)&qbase[(size_t)(qt * 64 + row) * J3 + c4 * 4];
        v.x *= scale; v.y *= scale; v.z *= scale; v.w *= scale;
        *(float4*)&Qs[row * 68 + c4 * 4] = v;
    }

    float m_i[4], l_i[4];
    float4 O[4];
    #pragma unroll
    for (int i = 0; i < 4; ++i) {
        m_i[i] = -INFINITY; l_i[i] = 0.f;
        O[i].x = 0.f; O[i].y = 0.f; O[i].z = 0.f; O[i].w = 0.f;
    }

    for (int kt = 0; kt < 16; ++kt) {
        __syncthreads();  // prev iter done with Ks(P)/Vs; Q visible on iter 0
        #pragma unroll
        for (int i = 0; i < 4; ++i) {
            int idx = t + 256 * i;
            int row = idx >> 4, c4 = idx & 15;
            const float* rb_ = &qbase[(size_t)(kt * 64 + row) * J3];
            *(float4*)&Ks[row * 68 + c4 * 4] = *(const float4*)&rb_[64 + c4 * 4];
            *(float4*)&Vs[row * 68 + c4 * 4] = *(const float4*)&rb_[128 + c4 * 4];
        }
        __syncthreads();

        // S = Q K^T  (4x4 per thread, float4 over d)
        float s[4][4];
        #pragma unroll
        for (int i = 0; i < 4; ++i)
            #pragma unroll
            for (int jx = 0; jx < 4; ++jx) s[i][jx] = 0.f;
        #pragma unroll
        for (int d4 = 0; d4 < 16; ++d4) {
            float4 q[4], kk[4];
            #pragma unroll
            for (int i = 0; i < 4; ++i)  q[i]  = *(const float4*)&Qs[(tr + i) * 68 + d4 * 4];
            #pragma unroll
            for (int jx = 0; jx < 4; ++jx) kk[jx] = *(const float4*)&Ks[(tj + jx) * 68 + d4 * 4];
            #pragma unroll
            for (int i = 0; i < 4; ++i)
                #pragma unroll
                for (int jx = 0; jx < 4; ++jx)
                    s[i][jx] += q[i].x * kk[jx].x + q[i].y * kk[jx].y +
                                q[i].z * kk[jx].z + q[i].w * kk[jx].w;
        }

        // Online softmax (per-row state; rows live in 16-lane groups)
        float p[4][4], alpha[4];
        #pragma unroll
        for (int i = 0; i < 4; ++i) {
            float mt = fmaxf(fmaxf(s[i][0], s[i][1]), fmaxf(s[i][2], s[i][3]));
            mt = fmaxf(mt, __shfl_xor(mt, 1));
            mt = fmaxf(mt, __shfl_xor(mt, 2));
            mt = fmaxf(mt, __shfl_xor(mt, 4));
            mt = fmaxf(mt, __shfl_xor(mt, 8));
            float mn = fmaxf(m_i[i], mt);
            alpha[i] = __expf(m_i[i] - mn);
            float rs = 0.f;
            #pragma unroll
            for (int jx = 0; jx < 4; ++jx) {
                p[i][jx] = __expf(s[i][jx] - mn);
                rs += p[i][jx];
            }
            rs += __shfl_xor(rs, 1);
            rs += __shfl_xor(rs, 2);
            rs += __shfl_xor(rs, 4);
            rs += __shfl_xor(rs, 8);
            l_i[i] = l_i[i] * alpha[i] + rs;
            m_i[i] = mn;
        }

        __syncthreads();  // everyone done reading Ks
        #pragma unroll
        for (int i = 0; i < 4; ++i) {
            float4 pv; pv.x = p[i][0]; pv.y = p[i][1]; pv.z = p[i][2]; pv.w = p[i][3];
            *(float4*)&Ks[(tr + i) * 68 + tj] = pv;   // P into Ks buffer
        }
        __syncthreads();  // P visible

        #pragma unroll
        for (int i = 0; i < 4; ++i) {
            O[i].x *= alpha[i]; O[i].y *= alpha[i];
            O[i].z *= alpha[i]; O[i].w *= alpha[i];
        }
        // O += P V  (thread owns rows tr.., output cols tj..)
        #pragma unroll
        for (int j4 = 0; j4 < 16; ++j4) {
            float pc[4][4];
            #pragma unroll
            for (int i = 0; i < 4; ++i) {
                float4 pv = *(const float4*)&Ks[(tr + i) * 68 + j4 * 4];
                pc[i][0] = pv.x; pc[i][1] = pv.y; pc[i][2] = pv.z; pc[i][3] = pv.w;
            }
            #pragma unroll
            for (int jj = 0; jj < 4; ++jj) {
                float4 v = *(const float4*)&Vs[(j4 * 4 + jj) * 68 + tj];
                #pragma unroll
                for (int i = 0; i < 4; ++i) {
                    O[i].x += pc[i][jj] * v.x;
                    O[i].y += pc[i][jj] * v.y;
                    O[i].z += pc[i][jj] * v.z;
                    O[i].w += pc[i][jj] * v.w;
                }
            }
        }
    }

    #pragma unroll
    for (int i = 0; i < 4; ++i) {
        float inv = 1.f / l_i[i];
        float4 o = O[i];
        o.x *= inv; o.y *= inv; o.z *= inv; o.w *= inv;
        int row = qt * 64 + tr + i;
        *(float4*)&res[((size_t)(b * NN + row)) * (NHEAD * DKK) + h * 64 + tj] = o;
    }
}

// ---------------- Kernel 3: out[b,c,n] = res[b,n,:]@W_out[:,c] + b_out[c] + x[b,c,n]
__global__ __launch_bounds__(256) void out_gemm(
    const float* __restrict__ res, const float* __restrict__ W,
    const float* __restrict__ bias, const float* __restrict__ x,
    float* __restrict__ out)
{
    __shared__ float As[16 * 65];   // [k][n], pad 65 to kill transpose-store conflicts
    __shared__ float Bs[16 * 64];   // [k][c]
    const int n0 = blockIdx.x * 64;
    const int c0 = blockIdx.y * 64;
    const int b  = blockIdx.z;
    const int t  = threadIdx.x;
    const int mm = t & 15;
    const int g  = t >> 4;
    const int tn = mm * 4;          // n fastest across lanes -> coalesced-ish stores
    const int tc = g * 4;

    float acc[4][4];                // [n i][c j]
    #pragma unroll
    for (int i = 0; i < 4; ++i)
        #pragma unroll
        for (int j = 0; j < 4; ++j) acc[i][j] = 0.f;

    for (int k0 = 0; k0 < 256; k0 += 16) {
        #pragma unroll
        for (int i = 0; i < 4; ++i) {
            int idx = t + 256 * i;
            int n = idx >> 4, k = idx & 15;
            As[k * 65 + n] = res[((size_t)(b * NN + n0 + n)) * 256 + k0 + k];
        }
        #pragma unroll
        for (int i = 0; i < 4; ++i) {
            int idx = t + 256 * i;
            int k = idx >> 6, c = idx & 63;
            Bs[k * 64 + c] = W[(size_t)(k0 + k) * 256 + c0 + c];
        }
        __syncthreads();
        #pragma unroll
        for (int k = 0; k < 16; ++k) {
            float a[4];
            #pragma unroll
            for (int i = 0; i < 4; ++i) a[i] = As[k * 65 + tn + i];
            float4 bv = *(const float4*)&Bs[k * 64 + tc];
            #pragma unroll
            for (int i = 0; i < 4; ++i) {
                acc[i][0] += a[i] * bv.x;
                acc[i][1] += a[i] * bv.y;
                acc[i][2] += a[i] * bv.z;
                acc[i][3] += a[i] * bv.w;
            }
        }
        __syncthreads();
    }

    float4 bv = *(const float4*)&bias[c0 + tc];
    float bcs[4] = {bv.x, bv.y, bv.z, bv.w};
    #pragma unroll
    for (int j = 0; j < 4; ++j) {
        int c = c0 + tc + j;
        const float* xrow = x + ((size_t)b * 256 + c) * NN + n0;
        float* orow = out + ((size_t)b * 256 + c) * NN + n0;
        #pragma unroll
        for (int i = 0; i < 4; ++i) {
            int n = tn + i;
            orow[n] = acc[i][j] + bcs[j] + xrow[n];
        }
    }
}

extern "C" void kernel_launch(void* const* d_in, const int* in_sizes, int n_in,
                              void* d_out, int out_size, void* d_ws, size_t ws_size,
                              hipStream_t stream)
{
    const float* x     = (const float*)d_in[0];
    const float* W_qkv = (const float*)d_in[1];
    const float* b_qkv = (const float*)d_in[2];
    const float* W_out = (const float*)d_in[3];
    const float* b_out = (const float*)d_in[4];
    float* out = (float*)d_out;

    float* qkv = (float*)d_ws;                                        // 16384*768 f32 = 48 MB
    float* res = (float*)((char*)d_ws + (size_t)16384 * 768 * 4);     // 16384*256 f32 = 16 MB

    qkv_gemm<<<dim3(6, 128), 256, 0, stream>>>(x, W_qkv, b_qkv, qkv);
    flash_attn<<<dim3(1024), 256, 0, stream>>>(qkv, res);
    out_gemm<<<dim3(16, 4, 16), 256, 0, stream>>>(res, W_out, b_out, x, out);
}

// Round 2
// 235.153 us; speedup vs baseline: 2.4504x; 2.4504x over previous
//
#include <hip/hip_runtime.h>
#include <math.h>

#define CCH  256
#define NN   1024    // 32*32
#define J3   768     // 4*64*3

typedef __attribute__((ext_vector_type(8))) __bf16 bf16x8;
typedef __attribute__((ext_vector_type(4))) float f32x4;

__device__ __forceinline__ unsigned short f2bf(float f) {
    unsigned u = __float_as_uint(f);
    unsigned r = (u + 0x7fff + ((u >> 16) & 1)) >> 16;   // RNE
    return (unsigned short)r;
}

// ---------------- Kernel 1: fp32 GEMM, bf16 epilogue -----------------------
// x: [B, C, N], W: [256, 768]. Outputs:
//   Qb [B,H,N,64] bf16 (pre-scaled by 0.125), Kb [B,H,N,64] bf16,
//   Vtb [B,H,64,N] bf16 (transposed for clean flash staging).
__global__ __launch_bounds__(256) void qkv_gemm(
    const float* __restrict__ x, const float* __restrict__ W,
    const float* __restrict__ bias,
    unsigned short* __restrict__ Qb, unsigned short* __restrict__ Kb,
    unsigned short* __restrict__ Vtb)
{
    __shared__ float As[16 * 128];   // [k][m]
    __shared__ float Bs[16 * 128];   // [k][j]
    const int j0 = blockIdx.x * 128;     // 768/128 = 6
    const int m0 = blockIdx.y * 128;     // 16384/128 = 128
    const int b  = m0 >> 10;
    const int n0 = m0 & 1023;            // tiles never straddle batches
    const int t  = threadIdx.x;
    const int g  = t >> 4;               // 0..15
    const int mm = t & 15;               // 0..15
    const float* xb = x + (size_t)b * CCH * NN + n0;

    float acc[2][4][2][4];               // [rowblk][i][colblk][j]
    #pragma unroll
    for (int rb = 0; rb < 2; ++rb)
        #pragma unroll
        for (int i = 0; i < 4; ++i)
            #pragma unroll
            for (int cb = 0; cb < 2; ++cb)
                #pragma unroll
                for (int j = 0; j < 4; ++j) acc[rb][i][cb][j] = 0.f;

    for (int k0 = 0; k0 < CCH; k0 += 16) {
        #pragma unroll
        for (int i = 0; i < 8; ++i) {
            int idx = t + 256 * i;
            int k = idx >> 7, p = idx & 127;
            As[k * 128 + p] = xb[(size_t)(k0 + k) * NN + p];
            Bs[k * 128 + p] = W[(size_t)(k0 + k) * J3 + j0 + p];
        }
        __syncthreads();
        #pragma unroll
        for (int k = 0; k < 16; ++k) {
            float4 a0 = *(const float4*)&As[k * 128 + 4 * g];
            float4 a1 = *(const float4*)&As[k * 128 + 64 + 4 * g];
            float4 b0 = *(const float4*)&Bs[k * 128 + 4 * mm];
            float4 b1 = *(const float4*)&Bs[k * 128 + 64 + 4 * mm];
            float ar[2][4] = {{a0.x, a0.y, a0.z, a0.w}, {a1.x, a1.y, a1.z, a1.w}};
            float br[2][4] = {{b0.x, b0.y, b0.z, b0.w}, {b1.x, b1.y, b1.z, b1.w}};
            #pragma unroll
            for (int rb = 0; rb < 2; ++rb)
                #pragma unroll
                for (int i = 0; i < 4; ++i)
                    #pragma unroll
                    for (int cb = 0; cb < 2; ++cb)
                        #pragma unroll
                        for (int j = 0; j < 4; ++j)
                            acc[rb][i][cb][j] += ar[rb][i] * br[cb][j];
        }
        __syncthreads();
    }

    float bb[2][4];
    #pragma unroll
    for (int cb = 0; cb < 2; ++cb) {
        float4 bv = *(const float4*)&bias[j0 + cb * 64 + 4 * mm];
        bb[cb][0] = bv.x; bb[cb][1] = bv.y; bb[cb][2] = bv.z; bb[cb][3] = bv.w;
    }

    #pragma unroll
    for (int cb = 0; cb < 2; ++cb) {
        const int chunk = blockIdx.x * 2 + cb;     // 0..11 (64-col chunks)
        const int h = chunk / 3;
        const int type = chunk - 3 * h;            // 0=q 1=k 2=v (uniform per cb)
        const size_t bh = (size_t)(b * 4 + h);
        if (type == 2) {
            // V: transposed store Vtb[bh][d][n], pack 4 consecutive n (rows i)
            #pragma unroll
            for (int rb = 0; rb < 2; ++rb)
                #pragma unroll
                for (int jj = 0; jj < 4; ++jj) {
                    int d = 4 * mm + jj;
                    ushort4 v;
                    v.x = f2bf(acc[rb][0][cb][jj] + bb[cb][jj]);
                    v.y = f2bf(acc[rb][1][cb][jj] + bb[cb][jj]);
                    v.z = f2bf(acc[rb][2][cb][jj] + bb[cb][jj]);
                    v.w = f2bf(acc[rb][3][cb][jj] + bb[cb][jj]);
                    *(ushort4*)&Vtb[(bh * 64 + d) * NN + n0 + rb * 64 + 4 * g] = v;
                }
        } else {
            unsigned short* dst = (type == 0) ? Qb : Kb;
            const float sc = (type == 0) ? 0.125f : 1.0f;   // 64^-0.5 folded into Q
            #pragma unroll
            for (int rb = 0; rb < 2; ++rb)
                #pragma unroll
                for (int i = 0; i < 4; ++i) {
                    int n = n0 + rb * 64 + 4 * g + i;
                    ushort4 v;
                    v.x = f2bf((acc[rb][i][cb][0] + bb[cb][0]) * sc);
                    v.y = f2bf((acc[rb][i][cb][1] + bb[cb][1]) * sc);
                    v.z = f2bf((acc[rb][i][cb][2] + bb[cb][2]) * sc);
                    v.w = f2bf((acc[rb][i][cb][3] + bb[cb][3]) * sc);
                    *(ushort4*)&dst[(bh * NN + n) * 64 + 4 * mm] = v;
                }
        }
    }
}

// ---------------- Kernel 2: bf16-MFMA flash attention ----------------------
// Per block: (b, h, 64-row Q tile). 4 waves; wave w owns Q rows [w*16, w*16+16).
// S^T = K·Q^T orientation: softmax row index = lane&15; P round-trips LDS.
__global__ __launch_bounds__(256, 4) void flash_attn(
    const unsigned short* __restrict__ Qb, const unsigned short* __restrict__ Kb,
    const unsigned short* __restrict__ Vtb, float* __restrict__ res)
{
    __shared__ __align__(16) unsigned short Qs[64 * 72];
    __shared__ __align__(16) unsigned short Ks[64 * 72];
    __shared__ __align__(16) unsigned short Vt[64 * 72];   // Vt[d][j]
    __shared__ __align__(16) unsigned short Ps[64 * 72];   // P[m][j], per-wave rows

    const int blk = blockIdx.x;
    const int qt = blk & 15;
    const int h  = (blk >> 4) & 3;
    const int b  = blk >> 6;
    const int t  = threadIdx.x;
    const int w  = t >> 6;
    const int lane = t & 63;
    const int quad = lane >> 4;
    const int c    = lane & 15;

    const size_t bh = (size_t)(b * 4 + h);
    const unsigned short* Qg = Qb  + bh * NN * 64;
    const unsigned short* Kg = Kb  + bh * NN * 64;
    const unsigned short* Vg = Vtb + bh * 64 * NN;

    // Stage Q tile once: 64 rows x 64 bf16
    #pragma unroll
    for (int i = 0; i < 2; ++i) {
        int flat = t + 256 * i;              // 512 chunks of 8 bf16
        int row = flat >> 3, seg = flat & 7;
        *(uint4*)&Qs[row * 72 + seg * 8] =
            *(const uint4*)&Qg[(size_t)(qt * 64 + row) * 64 + seg * 8];
    }

    float m_i = -INFINITY, l_i = 0.f;        // stats for q-row m = c (repl. across quads)
    f32x4 O[4];                              // O[row=quad*4+reg][d = dt*16 + c]
    #pragma unroll
    for (int dt = 0; dt < 4; ++dt) O[dt] = (f32x4)(0.f);

    for (int kt = 0; kt < 16; ++kt) {
        __syncthreads();                     // prev iter done with Ks/Vt (Q safe iter 0)
        #pragma unroll
        for (int i = 0; i < 2; ++i) {
            int flat = t + 256 * i;
            int row = flat >> 3, seg = flat & 7;
            *(uint4*)&Ks[row * 72 + seg * 8] =
                *(const uint4*)&Kg[(size_t)(kt * 64 + row) * 64 + seg * 8];
            *(uint4*)&Vt[row * 72 + seg * 8] =
                *(const uint4*)&Vg[(size_t)row * NN + kt * 64 + seg * 8];
        }
        __syncthreads();

        // S^T tile: rows j = jt*16 + quad*4 + reg, col m = c (this wave's q-rows)
        f32x4 S[4];
        #pragma unroll
        for (int jt = 0; jt < 4; ++jt) S[jt] = (f32x4)(0.f);
        #pragma unroll
        for (int ks = 0; ks < 2; ++ks) {
            bf16x8 qf = *(bf16x8*)&Qs[(w * 16 + c) * 72 + ks * 32 + quad * 8];
            #pragma unroll
            for (int jt = 0; jt < 4; ++jt) {
                bf16x8 kf = *(bf16x8*)&Ks[(jt * 16 + c) * 72 + ks * 32 + quad * 8];
                S[jt] = __builtin_amdgcn_mfma_f32_16x16x32_bf16(kf, qf, S[jt], 0, 0, 0);
            }
        }

        // Online softmax over j (16 values/lane, then reduce across quads)
        float mt = -INFINITY;
        #pragma unroll
        for (int jt = 0; jt < 4; ++jt)
            #pragma unroll
            for (int r = 0; r < 4; ++r) mt = fmaxf(mt, S[jt][r]);
        mt = fmaxf(mt, __shfl_xor(mt, 16));
        mt = fmaxf(mt, __shfl_xor(mt, 32));
        float mn = fmaxf(m_i, mt);
        float alpha = __expf(m_i - mn);
        float p[4][4];
        float rs = 0.f;
        #pragma unroll
        for (int jt = 0; jt < 4; ++jt)
            #pragma unroll
            for (int r = 0; r < 4; ++r) {
                p[jt][r] = __expf(S[jt][r] - mn);
                rs += p[jt][r];
            }
        rs += __shfl_xor(rs, 16);
        rs += __shfl_xor(rs, 32);
        l_i = l_i * alpha + rs;
        m_i = mn;

        // P -> LDS (own wave's rows only; no barrier needed)
        #pragma unroll
        for (int jt = 0; jt < 4; ++jt) {
            ushort4 pv;
            pv.x = f2bf(p[jt][0]); pv.y = f2bf(p[jt][1]);
            pv.z = f2bf(p[jt][2]); pv.w = f2bf(p[jt][3]);
            *(ushort4*)&Ps[(w * 16 + c) * 72 + jt * 16 + quad * 4] = pv;
        }

        // Rescale O by alpha of row quad*4+reg
        float alpha_r[4];
        #pragma unroll
        for (int r = 0; r < 4; ++r) alpha_r[r] = __shfl(alpha, quad * 4 + r);
        #pragma unroll
        for (int dt = 0; dt < 4; ++dt)
            #pragma unroll
            for (int r = 0; r < 4; ++r) O[dt][r] *= alpha_r[r];

        // O += P·V
        #pragma unroll
        for (int js = 0; js < 2; ++js) {
            bf16x8 pf = *(bf16x8*)&Ps[(w * 16 + c) * 72 + js * 32 + quad * 8];
            #pragma unroll
            for (int dt = 0; dt < 4; ++dt) {
                bf16x8 vf = *(bf16x8*)&Vt[(dt * 16 + c) * 72 + js * 32 + quad * 8];
                O[dt] = __builtin_amdgcn_mfma_f32_16x16x32_bf16(pf, vf, O[dt], 0, 0, 0);
            }
        }
    }

    // Epilogue: divide by l (per-row), store fp32 res[b*N + n][h*64 + d]
    float linv[4];
    #pragma unroll
    for (int r = 0; r < 4; ++r) linv[r] = 1.f / __shfl(l_i, quad * 4 + r);
    #pragma unroll
    for (int dt = 0; dt < 4; ++dt)
        #pragma unroll
        for (int r = 0; r < 4; ++r) {
            int row = qt * 64 + w * 16 + quad * 4 + r;
            res[((size_t)(b * NN + row)) * 256 + h * 64 + dt * 16 + c] = O[dt][r] * linv[r];
        }
}

// ---------------- Kernel 3: out[b,c,n] = res[b,n,:]@W_out[:,c] + b_out[c] + x[b,c,n]
__global__ __launch_bounds__(256) void out_gemm(
    const float* __restrict__ res, const float* __restrict__ W,
    const float* __restrict__ bias, const float* __restrict__ x,
    float* __restrict__ out)
{
    __shared__ float As[16 * 65];
    __shared__ float Bs[16 * 64];
    const int n0 = blockIdx.x * 64;
    const int c0 = blockIdx.y * 64;
    const int b  = blockIdx.z;
    const int t  = threadIdx.x;
    const int mm = t & 15;
    const int g  = t >> 4;
    const int tn = mm * 4;
    const int tc = g * 4;

    float acc[4][4];
    #pragma unroll
    for (int i = 0; i < 4; ++i)
        #pragma unroll
        for (int j = 0; j < 4; ++j) acc[i][j] = 0.f;

    for (int k0 = 0; k0 < 256; k0 += 16) {
        #pragma unroll
        for (int i = 0; i < 4; ++i) {
            int idx = t + 256 * i;
            int n = idx >> 4, k = idx & 15;
            As[k * 65 + n] = res[((size_t)(b * NN + n0 + n)) * 256 + k0 + k];
        }
        #pragma unroll
        for (int i = 0; i < 4; ++i) {
            int idx = t + 256 * i;
            int k = idx >> 6, c = idx & 63;
            Bs[k * 64 + c] = W[(size_t)(k0 + k) * 256 + c0 + c];
        }
        __syncthreads();
        #pragma unroll
        for (int k = 0; k < 16; ++k) {
            float a[4];
            #pragma unroll
            for (int i = 0; i < 4; ++i) a[i] = As[k * 65 + tn + i];
            float4 bv = *(const float4*)&Bs[k * 64 + tc];
            #pragma unroll
            for (int i = 0; i < 4; ++i) {
                acc[i][0] += a[i] * bv.x;
                acc[i][1] += a[i] * bv.y;
                acc[i][2] += a[i] * bv.z;
                acc[i][3] += a[i] * bv.w;
            }
        }
        __syncthreads();
    }

    float4 bv = *(const float4*)&bias[c0 + tc];
    float bcs[4] = {bv.x, bv.y, bv.z, bv.w};
    #pragma unroll
    for (int j = 0; j < 4; ++j) {
        int c = c0 + tc + j;
        const float* xrow = x + ((size_t)b * 256 + c) * NN + n0;
        float* orow = out + ((size_t)b * 256 + c) * NN + n0;
        #pragma unroll
        for (int i = 0; i < 4; ++i) {
            int n = tn + i;
            orow[n] = acc[i][j] + bcs[j] + xrow[n];
        }
    }
}

extern "C" void kernel_launch(void* const* d_in, const int* in_sizes, int n_in,
                              void* d_out, int out_size, void* d_ws, size_t ws_size,
                              hipStream_t stream)
{
    const float* x     = (const float*)d_in[0];
    const float* W_qkv = (const float*)d_in[1];
    const float* b_qkv = (const float*)d_in[2];
    const float* W_out = (const float*)d_in[3];
    const float* b_out = (const float*)d_in[4];
    float* out = (float*)d_out;

    // ws layout: Qb 8MB | Kb 8MB | Vtb 8MB | res fp32 16MB  = 40MB
    unsigned short* Qb  = (unsigned short*)d_ws;
    unsigned short* Kb  = (unsigned short*)((char*)d_ws + (size_t)8  * 1024 * 1024);
    unsigned short* Vtb = (unsigned short*)((char*)d_ws + (size_t)16 * 1024 * 1024);
    float*          res = (float*)((char*)d_ws + (size_t)24 * 1024 * 1024);

    qkv_gemm<<<dim3(6, 128), 256, 0, stream>>>(x, W_qkv, b_qkv, Qb, Kb, Vtb);
    flash_attn<<<dim3(1024), 256, 0, stream>>>(Qb, Kb, Vtb, res);
    out_gemm<<<dim3(16, 4, 16), 256, 0, stream>>>(res, W_out, b_out, x, out);
}

// Round 4
// 147.596 us; speedup vs baseline: 3.9041x; 1.5932x over previous
//
#include <hip/hip_runtime.h>
#include <math.h>

#define NN 1024    // 32*32 tokens per batch

typedef __attribute__((ext_vector_type(8))) __bf16 bf16x8;
typedef __attribute__((ext_vector_type(4))) float f32x4;

__device__ __forceinline__ unsigned short f2bf(float f) {
    unsigned u = __float_as_uint(f);
    unsigned r = (u + 0x7fff + ((u >> 16) & 1)) >> 16;   // RNE
    return (unsigned short)r;
}

// ---------------- Kernel 0: transpose + bf16 prep --------------------------
// x [16][256][1024] f32 -> xb [16*1024][256] bf16        (256 col-tiles x16 b)
// W_qkv [256][768] f32  -> Wqt [768][256] bf16           (12 col-tiles)
// W_out [256][256] f32  -> Wot [256][256] bf16 (transp)  (4 col-tiles)
__global__ __launch_bounds__(256) void prep_transpose(
    const float* __restrict__ x, const float* __restrict__ Wq,
    const float* __restrict__ Wo,
    unsigned short* __restrict__ xb, unsigned short* __restrict__ Wqt,
    unsigned short* __restrict__ Wot)
{
    __shared__ __align__(16) unsigned short T[64 * 72];  // [r][c] bf16, pad 72
    const int bx = blockIdx.x;   // 0..271
    const int rt = blockIdx.y;   // row tile (of 256 rows) 0..3
    const float* src; unsigned short* dst; int ncol, c0;
    if (bx < 256) {
        int b = bx >> 4; int ct = bx & 15;
        src = x + (size_t)b * 256 * 1024; dst = xb + (size_t)b * 1024 * 256;
        ncol = 1024; c0 = ct * 64;
    } else if (bx < 268) {
        src = Wq; dst = Wqt; ncol = 768; c0 = (bx - 256) * 64;
    } else {
        src = Wo; dst = Wot; ncol = 256; c0 = (bx - 268) * 64;
    }
    const int t = threadIdx.x;
    #pragma unroll
    for (int i = 0; i < 4; ++i) {
        int r  = i * 16 + (t >> 4);
        int c4 = (t & 15) * 4;
        float4 v = *(const float4*)&src[(size_t)(rt * 64 + r) * ncol + c0 + c4];
        ushort4 u; u.x = f2bf(v.x); u.y = f2bf(v.y); u.z = f2bf(v.z); u.w = f2bf(v.w);
        *(ushort4*)&T[r * 72 + c4] = u;
    }
    __syncthreads();
    // column gather (2-way bank aliasing only) -> coalesced store
    #pragma unroll
    for (int i = 0; i < 2; ++i) {
        int task = t + 256 * i;          // 0..511
        int c = task & 63, rs = task >> 6;
        ushort u8[8];
        #pragma unroll
        for (int k = 0; k < 8; ++k) u8[k] = T[(rs * 8 + k) * 72 + c];
        *(uint4*)&dst[(size_t)(c0 + c) * 256 + rt * 64 + rs * 8] = *(uint4*)u8;
    }
}

// ---------------- Kernel 1: bf16 MFMA QKV GEMM -----------------------------
// D[m][j] = xb[m][:] . Wqt[j][:]  (m = b*1024+n, j in 0..767)
// 128x128 tile, BK=32, 4 waves (2m x 2j), wave = 64x64 via 4x4 16x16x32 MFMAs.
// Epilogue: Qb/Kb [bh][n][64] (Q pre-scaled 0.125), Vtb [bh][64][n].
__global__ __launch_bounds__(256, 4) void qkv_gemm(
    const unsigned short* __restrict__ xb, const unsigned short* __restrict__ Wqt,
    const float* __restrict__ bias,
    unsigned short* __restrict__ Qb, unsigned short* __restrict__ Kb,
    unsigned short* __restrict__ Vtb)
{
    __shared__ __align__(16) unsigned short As[128 * 40];  // [m][k] stride 40
    __shared__ __align__(16) unsigned short Bs[128 * 40];  // [j][k]
    const int jt = blockIdx.x;        // 0..5
    const int m0 = blockIdx.y * 128;
    const int b  = m0 >> 10;
    const int n0 = m0 & 1023;
    const int t = threadIdx.x;
    const int w = t >> 6, lane = t & 63, quad = lane >> 4, cc = lane & 15;
    const int wm = (w & 1) * 64;
    const int wj = (w >> 1) * 64;

    f32x4 acc[4][4];
    #pragma unroll
    for (int ms = 0; ms < 4; ++ms)
        #pragma unroll
        for (int js = 0; js < 4; ++js) acc[ms][js] = (f32x4)(0.f);

    for (int k0 = 0; k0 < 256; k0 += 32) {
        __syncthreads();
        #pragma unroll
        for (int i = 0; i < 2; ++i) {
            int flat = t + 256 * i;
            int row = flat >> 2, seg = flat & 3;
            *(uint4*)&As[row * 40 + seg * 8] =
                *(const uint4*)&xb[(size_t)(m0 + row) * 256 + k0 + seg * 8];
            *(uint4*)&Bs[row * 40 + seg * 8] =
                *(const uint4*)&Wqt[(size_t)(jt * 128 + row) * 256 + k0 + seg * 8];
        }
        __syncthreads();
        bf16x8 af[4], bfr[4];
        #pragma unroll
        for (int ms = 0; ms < 4; ++ms)
            af[ms] = *(bf16x8*)&As[(wm + ms * 16 + cc) * 40 + quad * 8];
        #pragma unroll
        for (int js = 0; js < 4; ++js)
            bfr[js] = *(bf16x8*)&Bs[(wj + js * 16 + cc) * 40 + quad * 8];
        #pragma unroll
        for (int ms = 0; ms < 4; ++ms)
            #pragma unroll
            for (int js = 0; js < 4; ++js)
                acc[ms][js] = __builtin_amdgcn_mfma_f32_16x16x32_bf16(
                    af[ms], bfr[js], acc[ms][js], 0, 0, 0);
    }

    // wave's 64 j-columns = one uniform 64-chunk: chunk = jt*2 + (w>>1)
    const int chunk = jt * 2 + (w >> 1);
    const int h = chunk / 3, type = chunk % 3;   // 0=q 1=k 2=v
    const size_t bh = (size_t)b * 4 + h;
    float bias_r[4];
    #pragma unroll
    for (int js = 0; js < 4; ++js) bias_r[js] = bias[jt * 128 + wj + js * 16 + cc];

    if (type == 2) {
        // Vtb[bh][d][n]: lane owns row d = js*16+cc, ushort4 along n (regs)
        #pragma unroll
        for (int ms = 0; ms < 4; ++ms)
            #pragma unroll
            for (int js = 0; js < 4; ++js) {
                int dd = js * 16 + cc;
                int n = n0 + wm + ms * 16 + quad * 4;
                ushort4 u;
                u.x = f2bf(acc[ms][js][0] + bias_r[js]);
                u.y = f2bf(acc[ms][js][1] + bias_r[js]);
                u.z = f2bf(acc[ms][js][2] + bias_r[js]);
                u.w = f2bf(acc[ms][js][3] + bias_r[js]);
                *(ushort4*)&Vtb[(bh * 64 + dd) * NN + n] = u;
            }
    } else {
        unsigned short* dst = type ? Kb : Qb;
        const float sc = type ? 1.0f : 0.125f;   // 64^-0.5 folded into Q
        #pragma unroll
        for (int ms = 0; ms < 4; ++ms)
            #pragma unroll
            for (int js = 0; js < 4; ++js)
                #pragma unroll
                for (int r = 0; r < 4; ++r) {
                    int n = n0 + wm + ms * 16 + quad * 4 + r;
                    dst[(bh * NN + n) * 64 + js * 16 + cc] =
                        f2bf((acc[ms][js][r] + bias_r[js]) * sc);
                }
    }
}

// ---------------- Kernel 2: bf16-MFMA flash attention ----------------------
__global__ __launch_bounds__(256, 4) void flash_attn(
    const unsigned short* __restrict__ Qb, const unsigned short* __restrict__ Kb,
    const unsigned short* __restrict__ Vtb, unsigned short* __restrict__ resb)
{
    __shared__ __align__(16) unsigned short Qs[64 * 72];
    __shared__ __align__(16) unsigned short Ks[64 * 72];
    __shared__ __align__(16) unsigned short Vt[64 * 72];
    __shared__ __align__(16) unsigned short Ps[64 * 72];

    const int blk = blockIdx.x;
    const int qt = blk & 15;
    const int h  = (blk >> 4) & 3;
    const int b  = blk >> 6;
    const int t  = threadIdx.x;
    const int w  = t >> 6;
    const int lane = t & 63;
    const int quad = lane >> 4;
    const int c    = lane & 15;

    const size_t bh = (size_t)(b * 4 + h);
    const unsigned short* Qg = Qb  + bh * NN * 64;
    const unsigned short* Kg = Kb  + bh * NN * 64;
    const unsigned short* Vg = Vtb + bh * 64 * NN;

    #pragma unroll
    for (int i = 0; i < 2; ++i) {
        int flat = t + 256 * i;
        int row = flat >> 3, seg = flat & 7;
        *(uint4*)&Qs[row * 72 + seg * 8] =
            *(const uint4*)&Qg[(size_t)(qt * 64 + row) * 64 + seg * 8];
    }

    float m_i = -INFINITY, l_i = 0.f;
    f32x4 O[4];
    #pragma unroll
    for (int dt = 0; dt < 4; ++dt) O[dt] = (f32x4)(0.f);

    for (int kt = 0; kt < 16; ++kt) {
        __syncthreads();
        #pragma unroll
        for (int i = 0; i < 2; ++i) {
            int flat = t + 256 * i;
            int row = flat >> 3, seg = flat & 7;
            *(uint4*)&Ks[row * 72 + seg * 8] =
                *(const uint4*)&Kg[(size_t)(kt * 64 + row) * 64 + seg * 8];
            *(uint4*)&Vt[row * 72 + seg * 8] =
                *(const uint4*)&Vg[(size_t)row * NN + kt * 64 + seg * 8];
        }
        __syncthreads();

        f32x4 S[4];
        #pragma unroll
        for (int jt = 0; jt < 4; ++jt) S[jt] = (f32x4)(0.f);
        #pragma unroll
        for (int ks = 0; ks < 2; ++ks) {
            bf16x8 qf = *(bf16x8*)&Qs[(w * 16 + c) * 72 + ks * 32 + quad * 8];
            #pragma unroll
            for (int jt = 0; jt < 4; ++jt) {
                bf16x8 kf = *(bf16x8*)&Ks[(jt * 16 + c) * 72 + ks * 32 + quad * 8];
                S[jt] = __builtin_amdgcn_mfma_f32_16x16x32_bf16(kf, qf, S[jt], 0, 0, 0);
            }
        }

        float mt = -INFINITY;
        #pragma unroll
        for (int jt = 0; jt < 4; ++jt)
            #pragma unroll
            for (int r = 0; r < 4; ++r) mt = fmaxf(mt, S[jt][r]);
        mt = fmaxf(mt, __shfl_xor(mt, 16));
        mt = fmaxf(mt, __shfl_xor(mt, 32));
        float mn = fmaxf(m_i, mt);
        float alpha = __expf(m_i - mn);
        float p[4][4];
        float rs = 0.f;
        #pragma unroll
        for (int jt = 0; jt < 4; ++jt)
            #pragma unroll
            for (int r = 0; r < 4; ++r) {
                p[jt][r] = __expf(S[jt][r] - mn);
                rs += p[jt][r];
            }
        rs += __shfl_xor(rs, 16);
        rs += __shfl_xor(rs, 32);
        l_i = l_i * alpha + rs;
        m_i = mn;

        #pragma unroll
        for (int jt = 0; jt < 4; ++jt) {
            ushort4 pv;
            pv.x = f2bf(p[jt][0]); pv.y = f2bf(p[jt][1]);
            pv.z = f2bf(p[jt][2]); pv.w = f2bf(p[jt][3]);
            *(ushort4*)&Ps[(w * 16 + c) * 72 + jt * 16 + quad * 4] = pv;
        }

        float alpha_r[4];
        #pragma unroll
        for (int r = 0; r < 4; ++r) alpha_r[r] = __shfl(alpha, quad * 4 + r);
        #pragma unroll
        for (int dt = 0; dt < 4; ++dt)
            #pragma unroll
            for (int r = 0; r < 4; ++r) O[dt][r] *= alpha_r[r];

        #pragma unroll
        for (int js = 0; js < 2; ++js) {
            bf16x8 pf = *(bf16x8*)&Ps[(w * 16 + c) * 72 + js * 32 + quad * 8];
            #pragma unroll
            for (int dt = 0; dt < 4; ++dt) {
                bf16x8 vf = *(bf16x8*)&Vt[(dt * 16 + c) * 72 + js * 32 + quad * 8];
                O[dt] = __builtin_amdgcn_mfma_f32_16x16x32_bf16(pf, vf, O[dt], 0, 0, 0);
            }
        }
    }

    float linv[4];
    #pragma unroll
    for (int r = 0; r < 4; ++r) linv[r] = 1.f / __shfl(l_i, quad * 4 + r);
    #pragma unroll
    for (int dt = 0; dt < 4; ++dt)
        #pragma unroll
        for (int r = 0; r < 4; ++r) {
            int row = qt * 64 + w * 16 + quad * 4 + r;
            resb[((size_t)(b * NN + row)) * 256 + h * 64 + dt * 16 + c] =
                f2bf(O[dt][r] * linv[r]);
        }
}

// ---------------- Kernel 3: bf16 MFMA out GEMM + bias + residual -----------
// out[b][c][n] = res[b*1024+n][:] . Wot[c][:] + b_out[c] + x[b][c][n]
// 64x64 tile, 4 waves (2m x 2j), wave = 32x32 via 2x2 MFMAs. f32 output.
__global__ __launch_bounds__(256, 4) void out_gemm(
    const unsigned short* __restrict__ resb, const unsigned short* __restrict__ Wot,
    const float* __restrict__ bias, const float* __restrict__ x,
    float* __restrict__ out)
{
    __shared__ __align__(16) unsigned short As[64 * 40];  // res [m][k]
    __shared__ __align__(16) unsigned short Bs[64 * 40];  // Wot [j][k]
    const int n0 = blockIdx.x * 64;
    const int c0 = blockIdx.y * 64;
    const int b  = blockIdx.z;
    const int t = threadIdx.x;
    const int w = t >> 6, lane = t & 63, quad = lane >> 4, cc = lane & 15;
    const int wm = (w & 1) * 32;
    const int wj = (w >> 1) * 32;

    f32x4 acc[2][2];
    #pragma unroll
    for (int ms = 0; ms < 2; ++ms)
        #pragma unroll
        for (int js = 0; js < 2; ++js) acc[ms][js] = (f32x4)(0.f);

    for (int k0 = 0; k0 < 256; k0 += 32) {
        __syncthreads();
        {
            // FIX(R3 bug): stage ALL 64 rows of both tiles.
            // 256 threads: r = t>>2 in 0..63, seg = t&3 -> 64 rows x 32 k each.
            int r = t >> 2, seg = t & 3;
            *(uint4*)&As[r * 40 + seg * 8] =
                *(const uint4*)&resb[((size_t)b * NN + n0 + r) * 256 + k0 + seg * 8];
            *(uint4*)&Bs[r * 40 + seg * 8] =
                *(const uint4*)&Wot[(size_t)(c0 + r) * 256 + k0 + seg * 8];
        }
        __syncthreads();
        bf16x8 af[2], bfr[2];
        #pragma unroll
        for (int ms = 0; ms < 2; ++ms)
            af[ms] = *(bf16x8*)&As[(wm + ms * 16 + cc) * 40 + quad * 8];
        #pragma unroll
        for (int js = 0; js < 2; ++js)
            bfr[js] = *(bf16x8*)&Bs[(wj + js * 16 + cc) * 40 + quad * 8];
        #pragma unroll
        for (int ms = 0; ms < 2; ++ms)
            #pragma unroll
            for (int js = 0; js < 2; ++js)
                acc[ms][js] = __builtin_amdgcn_mfma_f32_16x16x32_bf16(
                    af[ms], bfr[js], acc[ms][js], 0, 0, 0);
    }

    #pragma unroll
    for (int js = 0; js < 2; ++js) {
        int c = c0 + wj + js * 16 + cc;
        float bi = bias[c];
        #pragma unroll
        for (int ms = 0; ms < 2; ++ms) {
            int n = n0 + wm + ms * 16 + quad * 4;
            size_t off = ((size_t)b * 256 + c) * NN + n;
            float4 xr = *(const float4*)&x[off];
            float4 o;
            o.x = acc[ms][js][0] + bi + xr.x;
            o.y = acc[ms][js][1] + bi + xr.y;
            o.z = acc[ms][js][2] + bi + xr.z;
            o.w = acc[ms][js][3] + bi + xr.w;
            *(float4*)&out[off] = o;
        }
    }
}

extern "C" void kernel_launch(void* const* d_in, const int* in_sizes, int n_in,
                              void* d_out, int out_size, void* d_ws, size_t ws_size,
                              hipStream_t stream)
{
    const float* x     = (const float*)d_in[0];
    const float* W_qkv = (const float*)d_in[1];
    const float* b_qkv = (const float*)d_in[2];
    const float* W_out = (const float*)d_in[3];
    const float* b_out = (const float*)d_in[4];
    float* out = (float*)d_out;

    // ws: xb 8MB | Wqt 384KB | Wot 128KB | Qb 8MB | Kb 8MB | Vtb 8MB | resb 8MB
    char* wsc = (char*)d_ws;
    unsigned short* xb   = (unsigned short*)(wsc);
    unsigned short* Wqt  = (unsigned short*)(wsc + ((size_t)8 << 20));
    unsigned short* Wot  = (unsigned short*)(wsc + ((size_t)8 << 20) + ((size_t)512 << 10));
    unsigned short* Qb   = (unsigned short*)(wsc + ((size_t)9  << 20));
    unsigned short* Kb   = (unsigned short*)(wsc + ((size_t)17 << 20));
    unsigned short* Vtb  = (unsigned short*)(wsc + ((size_t)25 << 20));
    unsigned short* resb = (unsigned short*)(wsc + ((size_t)33 << 20));

    prep_transpose<<<dim3(272, 4), 256, 0, stream>>>(x, W_qkv, W_out, xb, Wqt, Wot);
    qkv_gemm<<<dim3(6, 128), 256, 0, stream>>>(xb, Wqt, b_qkv, Qb, Kb, Vtb);
    flash_attn<<<dim3(1024), 256, 0, stream>>>(Qb, Kb, Vtb, resb);
    out_gemm<<<dim3(16, 4, 16), 256, 0, stream>>>(resb, Wot, b_out, x, out);
}